// Round 1
// baseline (1920.708 us; speedup 1.0000x reference)
//
#include <hip/hip_runtime.h>
#include <cstdint>
#include <cstddef>

// ---- problem constants ----
#define D_IN   2048
#define STATE_N 16
#define SEQ_L  4096
#define BATCH  4
#define M_TOT  (BATCH * SEQ_L)   // 16384
#define NCAT   (3 * D_IN)        // 6144

typedef __bf16 bf16x8 __attribute__((ext_vector_type(8)));
typedef float  f32x4  __attribute__((ext_vector_type(4)));
typedef unsigned int u32x4 __attribute__((ext_vector_type(4)));

__device__ __forceinline__ float softplus_f(float x) {
    return log1pf(expf(-fabsf(x))) + fmaxf(x, 0.f);
}
__device__ __forceinline__ unsigned short f2bf(float f) {  // RNE f32->bf16
    unsigned u = __float_as_uint(f);
    u += 0x7FFFu + ((u >> 16) & 1u);
    return (unsigned short)(u >> 16);
}
__device__ __forceinline__ float bf2f(unsigned short h) {
    return __uint_as_float(((unsigned)h) << 16);
}

// async global->LDS, 16B per lane (wave-uniform LDS base + lane*16 pattern)
__device__ __forceinline__ void gload_lds16(const unsigned short* g, unsigned short* l) {
    __builtin_amdgcn_global_load_lds(
        (const __attribute__((address_space(1))) unsigned int*)(const void*)g,
        (__attribute__((address_space(3))) unsigned int*)(void*)l,
        16, 0, 0);
}

// ---------------- u -> bf16 ----------------
__global__ __launch_bounds__(256) void k_cvt_u(const float* __restrict__ u,
                                               unsigned short* __restrict__ ub) {
    size_t i = ((size_t)blockIdx.x * 256 + threadIdx.x) * 8;
    f32x4 a = *(const f32x4*)(u + i);
    f32x4 b = *(const f32x4*)(u + i + 4);
    u32x4 o;
    o[0] = (unsigned)f2bf(a[0]) | ((unsigned)f2bf(a[1]) << 16);
    o[1] = (unsigned)f2bf(a[2]) | ((unsigned)f2bf(a[3]) << 16);
    o[2] = (unsigned)f2bf(b[0]) | ((unsigned)f2bf(b[1]) << 16);
    o[3] = (unsigned)f2bf(b[2]) | ((unsigned)f2bf(b[3]) << 16);
    *(u32x4*)(ub + i) = o;
}

// ---------------- W(cat) -> Wt bf16 (NCAT x K) ----------------
__global__ __launch_bounds__(256) void k_transpose(const float* __restrict__ Wdt,
                                                   const float* __restrict__ Wb,
                                                   const float* __restrict__ Wc,
                                                   unsigned short* __restrict__ Btb) {
    __shared__ float tile[32][33];
    int e0 = blockIdx.x * 32;   // column in cat space
    int k0 = blockIdx.y * 32;   // row of W
    const float* W; int eo;
    if (e0 >= 2 * D_IN)      { W = Wc; eo = e0 - 2 * D_IN; }
    else if (e0 >= D_IN)     { W = Wb; eo = e0 - D_IN; }
    else                     { W = Wdt; eo = e0; }
    int tx = threadIdx.x, ty = threadIdx.y;
#pragma unroll
    for (int i = ty; i < 32; i += 8)
        tile[i][tx] = W[(size_t)(k0 + i) * D_IN + eo + tx];
    __syncthreads();
#pragma unroll
    for (int i = ty; i < 32; i += 8)
        Btb[(size_t)(e0 + i) * D_IN + k0 + tx] = f2bf(tile[tx][i]);
}

// ---------------- fused projection GEMM ----------------
// out[m][e] = sum_k u[m][k] * Wcat[k][e];  e<2048 -> dt (softplus+DT_MIN, fp32)
// 2048..4095 -> b (bf16), 4096..6143 -> c (bf16)
__global__ __launch_bounds__(256) void k_gemm(const unsigned short* __restrict__ Au,
                                              const unsigned short* __restrict__ Btb,
                                              const float* __restrict__ bdt,
                                              const float* __restrict__ bbv,
                                              const float* __restrict__ bcv,
                                              float* __restrict__ dtp,
                                              unsigned short* __restrict__ btp,
                                              unsigned short* __restrict__ ctp) {
    __shared__ unsigned short As[128 * 32];
    __shared__ unsigned short Bs[128 * 32];
    int bn = blockIdx.x, bm = blockIdx.y;
    int tid = threadIdx.x;
    int lane = tid & 63, wave = tid >> 6;
    int wr = wave >> 1, wc = wave & 1;
    int l15 = lane & 15, lhi = lane >> 4;

    f32x4 acc[4][4] = {};

    const int c0 = tid, c1 = tid + 256;
    const int r0 = c0 >> 2, k0off = (c0 & 3) * 8;
    const int r1 = c1 >> 2, k1off = (c1 & 3) * 8;
    const unsigned short* Ag0 = Au + (size_t)(bm * 128 + r0) * D_IN + k0off;
    const unsigned short* Ag1 = Au + (size_t)(bm * 128 + r1) * D_IN + k1off;
    const unsigned short* Bg0 = Btb + (size_t)(bn * 128 + r0) * D_IN + k0off;
    const unsigned short* Bg1 = Btb + (size_t)(bn * 128 + r1) * D_IN + k1off;

    for (int kt = 0; kt < D_IN; kt += 32) {
        __syncthreads();
        gload_lds16(Ag0 + kt, &As[c0 * 8]);
        gload_lds16(Ag1 + kt, &As[c1 * 8]);
        gload_lds16(Bg0 + kt, &Bs[c0 * 8]);
        gload_lds16(Bg1 + kt, &Bs[c1 * 8]);
        __syncthreads();
        bf16x8 af[4], bfr[4];
#pragma unroll
        for (int i = 0; i < 4; ++i)
            af[i] = *(const bf16x8*)&As[(wr * 64 + i * 16 + l15) * 32 + lhi * 8];
#pragma unroll
        for (int j = 0; j < 4; ++j)
            bfr[j] = *(const bf16x8*)&Bs[(wc * 64 + j * 16 + l15) * 32 + lhi * 8];
#pragma unroll
        for (int i = 0; i < 4; ++i)
#pragma unroll
            for (int j = 0; j < 4; ++j)
                acc[i][j] = __builtin_amdgcn_mfma_f32_16x16x32_bf16(af[i], bfr[j], acc[i][j], 0, 0, 0);
    }

    int gm0 = bm * 128 + wr * 64 + lhi * 4;
    int gn0 = bn * 128 + wc * 64 + l15;
#pragma unroll
    for (int j = 0; j < 4; ++j) {
        int gn = gn0 + j * 16;
#pragma unroll
        for (int i = 0; i < 4; ++i) {
#pragma unroll
            for (int r = 0; r < 4; ++r) {
                int gm = gm0 + i * 16 + r;
                float v = acc[i][j][r];
                if (gn < D_IN) {
                    dtp[(size_t)gm * D_IN + gn] = softplus_f(v + bdt[gn]) + 1e-4f;
                } else if (gn < 2 * D_IN) {
                    btp[(size_t)gm * D_IN + (gn - D_IN)] = f2bf(v + bbv[gn - D_IN]);
                } else {
                    ctp[(size_t)gm * D_IN + (gn - 2 * D_IN)] = f2bf(v + bcv[gn - 2 * D_IN]);
                }
            }
        }
    }
}

// ---------------- selective scan ----------------
// thread = (b, d, n); 16 lanes (one d) reduce over n via shfl_xor.
__device__ __forceinline__ void load_chunk(const float* __restrict__ u,
                                           const float* __restrict__ dtp,
                                           const unsigned short* __restrict__ btp,
                                           const unsigned short* __restrict__ ctp,
                                           size_t base, int l0,
                                           float (&U)[8], float (&T)[8],
                                           float (&Bv)[8], float (&Cv)[8]) {
#pragma unroll
    for (int i = 0; i < 8; ++i) {
        size_t off = base + (size_t)(l0 + i) * D_IN;
        U[i] = u[off];
        T[i] = dtp[off];
        Bv[i] = bf2f(btp[off]);
        Cv[i] = bf2f(ctp[off]);
    }
}

__device__ __forceinline__ void comp_chunk(float& x, int n, float A2, float Bbase,
                                           float Cbase, float Dd,
                                           float* __restrict__ y, size_t base, int l0,
                                           const float (&U)[8], const float (&T)[8],
                                           const float (&Bv)[8], const float (&Cv)[8]) {
#pragma unroll
    for (int i = 0; i < 8; ++i) {
        float dtv = T[i], uv = U[i];
        float Ab = exp2f(A2 * dtv);
        x = fmaf(Ab, x, dtv * (Bv[i] * Bbase) * uv);
        float t = Cbase * x;
        t += __shfl_xor(t, 1);
        t += __shfl_xor(t, 2);
        t += __shfl_xor(t, 4);
        t += __shfl_xor(t, 8);
        if (n == 0) y[base + (size_t)(l0 + i) * D_IN] = fmaf(Dd, uv, Cv[i] * t);
    }
}

__global__ __launch_bounds__(256) void k_scan(const float* __restrict__ u,
                                              const float* __restrict__ dtp,
                                              const unsigned short* __restrict__ btp,
                                              const unsigned short* __restrict__ ctp,
                                              const float* __restrict__ a_raw,
                                              const float* __restrict__ Bbp,
                                              const float* __restrict__ Cbp,
                                              const float* __restrict__ Dv,
                                              float* __restrict__ carry,
                                              float* __restrict__ y) {
    int tid = threadIdx.x;
    int n = tid & 15, ld = tid >> 4;
    int d = blockIdx.x * 16 + ld;
    int b = blockIdx.y;

    float A2 = -softplus_f(a_raw[d * STATE_N + n]) * 1.4426950408889634f;
    float Bbase = Bbp[d * STATE_N + n];
    float Cbase = Cbp[d * STATE_N + n];
    float Dd = Dv[d];
    size_t base = ((size_t)b * SEQ_L) * D_IN + d;

    float x = 0.f;
    float aU[8], aT[8], aB[8], aC[8];
    float bU[8], bT[8], bB[8], bC[8];

    load_chunk(u, dtp, btp, ctp, base, 0, aU, aT, aB, aC);
    for (int c0 = 0; c0 < SEQ_L; c0 += 16) {
        load_chunk(u, dtp, btp, ctp, base, c0 + 8, bU, bT, bB, bC);
        comp_chunk(x, n, A2, Bbase, Cbase, Dd, y, base, c0, aU, aT, aB, aC);
        if (c0 + 16 < SEQ_L)
            load_chunk(u, dtp, btp, ctp, base, c0 + 16, aU, aT, aB, aC);
        comp_chunk(x, n, A2, Bbase, Cbase, Dd, y, base, c0 + 8, bU, bT, bB, bC);
    }
    carry[((size_t)b * D_IN + d) * STATE_N + n] = x;
}

// ---------------- launch ----------------
extern "C" void kernel_launch(void* const* d_in, const int* in_sizes, int n_in,
                              void* d_out, int out_size, void* d_ws, size_t ws_size,
                              hipStream_t stream) {
    const float* u     = (const float*)d_in[0];
    const float* Wdt   = (const float*)d_in[1];
    const float* bdt   = (const float*)d_in[2];
    const float* Wb    = (const float*)d_in[3];
    const float* bb    = (const float*)d_in[4];
    const float* Wc    = (const float*)d_in[5];
    const float* bc    = (const float*)d_in[6];
    const float* a_raw = (const float*)d_in[7];
    const float* Bbp   = (const float*)d_in[8];
    const float* Cbp   = (const float*)d_in[9];
    const float* Dv    = (const float*)d_in[10];

    float* out = (float*)d_out;
    float* carry = out;                                      // (B, d, N)
    float* y = out + (size_t)BATCH * D_IN * STATE_N;         // (B, L, d)

    char* ws = (char*)d_ws;
    unsigned short* ub  = (unsigned short*)ws;                               // 64 MiB
    unsigned short* Btb = (unsigned short*)(ws + (size_t)M_TOT * D_IN * 2);  // 24 MiB
    char* p = ws + (size_t)M_TOT * D_IN * 2 + (size_t)NCAT * D_IN * 2;
    float* dtp = (float*)p;                                  // 128 MiB fp32
    unsigned short* btp = (unsigned short*)(p + (size_t)M_TOT * D_IN * 4);   // 64 MiB
    unsigned short* ctp = (unsigned short*)(p + (size_t)M_TOT * D_IN * 4 + (size_t)M_TOT * D_IN * 2);

    k_cvt_u<<<dim3((M_TOT * D_IN) / (256 * 8)), dim3(256), 0, stream>>>(u, ub);
    k_transpose<<<dim3(NCAT / 32, D_IN / 32), dim3(32, 8), 0, stream>>>(Wdt, Wb, Wc, Btb);
    k_gemm<<<dim3(NCAT / 128, M_TOT / 128), dim3(256), 0, stream>>>(ub, Btb, bdt, bb, bc,
                                                                    dtp, btp, ctp);
    k_scan<<<dim3(D_IN / 16, BATCH), dim3(256), 0, stream>>>(u, dtp, btp, ctp, a_raw,
                                                             Bbp, Cbp, Dv, carry, y);
}